// Round 4
// baseline (214.190 us; speedup 1.0000x reference)
//
#include <hip/hip_runtime.h>
#include <math.h>

#define NV 778
#define NJ 16
#define NCOMP 24
#define NBETA 10
#define FC 1554
#define NA 32
#define NB 8
#define NOBJ 16384
#define VD (NV*3)          // 2334
#define NSLOT 13           // ceil(778/64)

// ---------------- Kernel 1: full MANO prep, one block per batch.
// pose -> shape blend (LDS) -> joints -> chain -> (pose blend + LBS fused)
// -> face normals (LDS atomics) -> normals/contact out.
__global__ __launch_bounds__(256) void k_prep(
    const float* __restrict__ hp, const float* __restrict__ pca,
    const float* __restrict__ beta, const float* __restrict__ vt,
    const float* __restrict__ sd, const float* __restrict__ pd,
    const float* __restrict__ Jreg, const float* __restrict__ W,
    const int* __restrict__ faces, const float* __restrict__ aw,
    const int* __restrict__ afi,
    float* __restrict__ verts, float4* __restrict__ PK,
    float* __restrict__ NRM, float* __restrict__ contact,
    float* __restrict__ pen)
{
    int b = blockIdx.x, t = threadIdx.x;
    int lane = t & 63, wid = t >> 6;
    __shared__ float  h45[45];
    __shared__ float  sR[NJ*9];
    __shared__ float4 PF4[34];        // pose_feat, 135 used + pad
    __shared__ float  sJ[NJ*3];
    __shared__ float4 sA4[NJ*3];      // A matrices, rows as float4 {r0,r1,r2,t}
    __shared__ float  svs[VD];        // v_shaped
    __shared__ float  sv[VD];         // final verts
    __shared__ float  sn[VD];         // normal accumulator

    // --- phase 0: PCA coeffs + zero normal accumulator
    if (t < 45) {
        float acc = 0.0f;
        for (int k = 0; k < NCOMP; ++k) acc += hp[b*30 + 6 + k] * pca[k*45 + t];
        h45[t] = acc;
    }
    for (int i = t; i < VD; i += 256) sn[i] = 0.0f;
    __syncthreads();

    // --- phase 1: Rodrigues (t<16) + shape blend (all threads)
    if (t < NJ) {
        float rx, ry, rz;
        if (t == 0) { rx = hp[b*30+3]; ry = hp[b*30+4]; rz = hp[b*30+5]; }
        else        { rx = h45[(t-1)*3]; ry = h45[(t-1)*3+1]; rz = h45[(t-1)*3+2]; }
        float th = sqrtf(rx*rx + ry*ry + rz*rz + 1e-16f);
        float kx = rx/th, ky = ry/th, kz = rz/th;
        float c = cosf(th), s = sinf(th), o = 1.0f - c;
        sR[t*9+0] = c + o*kx*kx;      sR[t*9+1] = -s*kz + o*kx*ky;  sR[t*9+2] =  s*ky + o*kx*kz;
        sR[t*9+3] =  s*kz + o*ky*kx;  sR[t*9+4] = c + o*ky*ky;      sR[t*9+5] = -s*kx + o*ky*kz;
        sR[t*9+6] = -s*ky + o*kz*kx;  sR[t*9+7] =  s*kx + o*kz*ky;  sR[t*9+8] = c + o*kz*kz;
    }
    {
        const float* bb = beta + b * NBETA;
        for (int r = t; r < VD; r += 256) {
            float vs = vt[r];
            const float* s = sd + r * NBETA;
            #pragma unroll
            for (int k = 0; k < NBETA; ++k) vs += s[k] * bb[k];
            svs[r] = vs;
        }
    }
    __syncthreads();

    // --- phase 2: pose_feat (reads sR) + joints (reads svs), concurrent
    if (t < 135) {
        int mn = t % 9;
        float d = (mn == 0 || mn == 4 || mn == 8) ? 1.0f : 0.0f;
        ((float*)PF4)[t] = sR[9 + t] - d;
    }
    if (t == 135) ((float*)PF4)[135] = 0.0f;   // pad
    {
        float ac[12];
        #pragma unroll
        for (int q = 0; q < 12; ++q) ac[q] = 0.0f;
        for (int v = lane; v < NV; v += 64) {
            float x = svs[v*3], y = svs[v*3+1], z = svs[v*3+2];
            #pragma unroll
            for (int jj = 0; jj < 4; ++jj) {
                float w = Jreg[(4*wid + jj)*NV + v];
                ac[jj*3+0] += w*x; ac[jj*3+1] += w*y; ac[jj*3+2] += w*z;
            }
        }
        #pragma unroll
        for (int q = 0; q < 12; ++q)
            for (int off = 32; off; off >>= 1) ac[q] += __shfl_down(ac[q], off, 64);
        if (lane == 0) {
            #pragma unroll
            for (int q = 0; q < 12; ++q) sJ[(4*wid + q/3)*3 + (q%3)] = ac[q];
        }
    }
    __syncthreads();

    // --- phase 3: kinematic chain, thread m (0..2) owns row m of all T's
    if (t < 3) {
        const int par[NJ] = {-1,0,1,2,0,4,5,0,7,8,0,10,11,0,13,14};
        int m = t;
        float Tr[NJ][3], Tt[NJ];
        Tr[0][0] = sR[m*3+0]; Tr[0][1] = sR[m*3+1]; Tr[0][2] = sR[m*3+2];
        Tt[0] = sJ[m];
        #pragma unroll
        for (int j = 1; j < NJ; ++j) {
            int p = par[j];
            float t0 = sJ[j*3+0] - sJ[p*3+0];
            float t1 = sJ[j*3+1] - sJ[p*3+1];
            float t2 = sJ[j*3+2] - sJ[p*3+2];
            float a0 = Tr[p][0], a1 = Tr[p][1], a2 = Tr[p][2];
            #pragma unroll
            for (int n = 0; n < 3; ++n)
                Tr[j][n] = a0*sR[j*9+n] + a1*sR[j*9+3+n] + a2*sR[j*9+6+n];
            Tt[j] = a0*t0 + a1*t1 + a2*t2 + Tt[p];
        }
        #pragma unroll
        for (int j = 0; j < NJ; ++j) {
            float corr = Tr[j][0]*sJ[j*3] + Tr[j][1]*sJ[j*3+1] + Tr[j][2]*sJ[j*3+2];
            sA4[j*3 + m] = make_float4(Tr[j][0], Tr[j][1], Tr[j][2], Tt[j] - corr);
        }
    }
    __syncthreads();

    // --- phase 4: pose blend + LBS fused, per vertex
    float tx = hp[b*30+0], ty = hp[b*30+1], tz = hp[b*30+2];
    for (int v = t; v < NV; v += 256) {
        const float* p0 = pd + v * 405;      // 3 rows of 135, contiguous
        float a0 = 0.f, a1 = 0.f, a2 = 0.f;
        #pragma unroll 4
        for (int kb = 0; kb < 33; ++kb) {    // 132 of 135 via float4 LDS reads
            float4 pf = PF4[kb];
            int k = kb * 4;
            a0 = fmaf(p0[k+0],     pf.x, a0); a0 = fmaf(p0[k+1],     pf.y, a0);
            a0 = fmaf(p0[k+2],     pf.z, a0); a0 = fmaf(p0[k+3],     pf.w, a0);
            a1 = fmaf(p0[135+k+0], pf.x, a1); a1 = fmaf(p0[135+k+1], pf.y, a1);
            a1 = fmaf(p0[135+k+2], pf.z, a1); a1 = fmaf(p0[135+k+3], pf.w, a1);
            a2 = fmaf(p0[270+k+0], pf.x, a2); a2 = fmaf(p0[270+k+1], pf.y, a2);
            a2 = fmaf(p0[270+k+2], pf.z, a2); a2 = fmaf(p0[270+k+3], pf.w, a2);
        }
        #pragma unroll
        for (int k = 132; k < 135; ++k) {    // tail
            float pf = ((const float*)PF4)[k];
            a0 = fmaf(p0[k], pf, a0);
            a1 = fmaf(p0[135+k], pf, a1);
            a2 = fmaf(p0[270+k], pf, a2);
        }
        float px = svs[v*3]   + a0;
        float py = svs[v*3+1] + a1;
        float pz = svs[v*3+2] + a2;
        // LBS
        float4 r0 = make_float4(0,0,0,0), r1 = make_float4(0,0,0,0), r2 = make_float4(0,0,0,0);
        const float* w = W + v * NJ;
        for (int j = 0; j < NJ; ++j) {
            float wj = w[j];
            float4 A0 = sA4[j*3+0], A1 = sA4[j*3+1], A2 = sA4[j*3+2];
            r0.x += wj*A0.x; r0.y += wj*A0.y; r0.z += wj*A0.z; r0.w += wj*A0.w;
            r1.x += wj*A1.x; r1.y += wj*A1.y; r1.z += wj*A1.z; r1.w += wj*A1.w;
            r2.x += wj*A2.x; r2.y += wj*A2.y; r2.z += wj*A2.z; r2.w += wj*A2.w;
        }
        int i = b*NV + v;
        float x = r0.x*px + r0.y*py + r0.z*pz + r0.w + tx;
        float y = r1.x*px + r1.y*py + r1.z*pz + r1.w + ty;
        float z = r2.x*px + r2.y*py + r2.z*pz + r2.w + tz;
        sv[v*3] = x; sv[v*3+1] = y; sv[v*3+2] = z;
        verts[i*3] = x; verts[i*3+1] = y; verts[i*3+2] = z;
        PK[i] = make_float4(x, y, z, 0.5f*(x*x + y*y + z*z));
    }
    __syncthreads();

    // --- phase 5: face normals into LDS accumulator
    for (int f = t; f < FC; f += 256) {
        int i0 = faces[f*3], i1 = faces[f*3+1], i2 = faces[f*3+2];
        float ax = sv[i1*3+0]-sv[i0*3+0], ay = sv[i1*3+1]-sv[i0*3+1], az = sv[i1*3+2]-sv[i0*3+2];
        float bx = sv[i2*3+0]-sv[i0*3+0], by = sv[i2*3+1]-sv[i0*3+1], bz = sv[i2*3+2]-sv[i0*3+2];
        float cx = ay*bz - az*by, cy = az*bx - ax*bz, cz = ax*by - ay*bx;
        atomicAdd(&sn[i0*3+0], cx); atomicAdd(&sn[i0*3+1], cy); atomicAdd(&sn[i0*3+2], cz);
        atomicAdd(&sn[i1*3+0], cx); atomicAdd(&sn[i1*3+1], cy); atomicAdd(&sn[i1*3+2], cz);
        atomicAdd(&sn[i2*3+0], cx); atomicAdd(&sn[i2*3+1], cy); atomicAdd(&sn[i2*3+2], cz);
    }
    __syncthreads();

    // --- phase 6: outputs
    for (int i = t; i < VD; i += 256) NRM[b*VD + i] = sn[i];
    if (t < NA*3) {
        int a = t / 3, d = t % 3;
        float acc = 0.0f;
        #pragma unroll
        for (int k = 0; k < 3; ++k)
            acc += aw[a*3 + k] * sv[afi[a*3 + k]*3 + d];
        contact[b*NA*3 + t] = acc;
    }
    if (b == 0 && t == 0) *pen = 0.0f;
}

// ---------------- Kernel 2: NN search + cmap + penetration (R3 design, measured-good).
// Each lane holds 13 verts in VGPRs; wave iterates its 64 obj points; broadcast
// via v_readlane (VALU); argmin via fminf butterfly + ballot + readlane.
__global__ __launch_bounds__(256) void k_nn(const float* __restrict__ obj,
                                            const float4* __restrict__ PK,
                                            const float* __restrict__ NRM,
                                            float* __restrict__ cmap,
                                            float* __restrict__ pen)
{
    int b = blockIdx.x >> 6;
    int n = (blockIdx.x & 63) * 256 + threadIdx.x;
    int t = threadIdx.x, lane = t & 63;
    int base = b * NV;

    float4 q[NSLOT];
    #pragma unroll
    for (int j = 0; j < NSLOT; ++j) {
        int idx = j*64 + lane;
        q[j] = (idx < NV) ? PK[base + idx] : make_float4(0.f, 0.f, 0.f, 1e30f);
    }
    const float* o = obj + (b*NOBJ + n)*3;
    float ox = o[0], oy = o[1], oz = o[2];

    float myS = 0.0f;
    int myI = 0;
    for (int p = 0; p < 64; ++p) {
        float bx = __uint_as_float(__builtin_amdgcn_readlane(__float_as_uint(ox), p));
        float by = __uint_as_float(__builtin_amdgcn_readlane(__float_as_uint(oy), p));
        float bz = __uint_as_float(__builtin_amdgcn_readlane(__float_as_uint(oz), p));
        float sb = 1e30f; int jb = 0;
        #pragma unroll
        for (int j = 0; j < NSLOT; ++j) {
            float s = fmaf(-bx, q[j].x, q[j].w);
            s = fmaf(-by, q[j].y, s);
            s = fmaf(-bz, q[j].z, s);
            if (s < sb) { sb = s; jb = j; }
        }
        int ifull = jb*64 + lane;
        float smin = sb;
        #pragma unroll
        for (int m = 1; m < 64; m <<= 1)
            smin = fminf(smin, __shfl_xor(smin, m, 64));
        unsigned long long mk = __ballot(sb == smin);
        int w = __ffsll(mk) - 1;
        int widx = __builtin_amdgcn_readlane(ifull, w);
        if (lane == p) { myS = smin; myI = widx; }
    }

    float osq = ox*ox + oy*oy + oz*oz;
    float d2 = 2.0f * myS + osq;
    cmap[b*NOBJ + n] = 2.0f / (1.0f + expf(100.0f * d2));

    float4 qq = PK[base + myI];
    float nx = NRM[(base + myI)*3 + 0];
    float ny = NRM[(base + myI)*3 + 1];
    float nz = NRM[(base + myI)*3 + 2];
    float dotp = (qq.x - ox)*nx + (qq.y - oy)*ny + (qq.z - oz)*nz;
    float p = (dotp > 0.0f) ? d2 : 0.0f;
    for (int off = 32; off; off >>= 1) p += __shfl_down(p, off, 64);
    __shared__ float wsum[4];
    if (lane == 0) wsum[t >> 6] = p;
    __syncthreads();
    if (t == 0) atomicAdd(pen, (wsum[0] + wsum[1] + wsum[2] + wsum[3]) * (1.0f / NB));
}

extern "C" void kernel_launch(void* const* d_in, const int* in_sizes, int n_in,
                              void* d_out, int out_size, void* d_ws, size_t ws_size,
                              hipStream_t stream)
{
    const float* hp    = (const float*)d_in[0];
    const float* obj   = (const float*)d_in[1];
    const float* beta  = (const float*)d_in[2];
    const float* vt    = (const float*)d_in[3];
    const float* sd    = (const float*)d_in[4];
    const float* pd    = (const float*)d_in[5];
    const float* Jreg  = (const float*)d_in[6];
    const float* W     = (const float*)d_in[7];
    const float* pca   = (const float*)d_in[8];
    const float* aw    = (const float*)d_in[9];
    const int*   faces = (const int*)d_in[10];
    const int*   afi   = (const int*)d_in[11];

    float* out     = (float*)d_out;
    float* cmap    = out;                          // 131072
    float* pen     = out + NB*NOBJ;                // 1
    float* verts   = out + NB*NOBJ + 1;            // 18672
    float* contact = out + NB*NOBJ + 1 + NB*NV*3;  // 768

    float* ws  = (float*)d_ws;
    float4* PK = (float4*)ws;        // NB*NV float4 (16B-aligned at base)
    float* NRM = ws + NB*NV*4;       // NB*VD

    k_prep<<<NB, 256, 0, stream>>>(hp, pca, beta, vt, sd, pd, Jreg, W,
                                   faces, aw, afi, verts, PK, NRM, contact, pen);
    k_nn  <<<NB*64, 256, 0, stream>>>(obj, PK, NRM, cmap, pen);
}

// Round 5
// 151.423 us; speedup vs baseline: 1.4145x; 1.4145x over previous
//
#include <hip/hip_runtime.h>
#include <math.h>

#define NV 778
#define NJ 16
#define NCOMP 24
#define NBETA 10
#define FC 1554
#define NA 32
#define NB 8
#define NOBJ 16384
#define VD (NV*3)          // 2334
#define NSLOT 13           // ceil(778/64)
#define BCH 584            // ceil(VD/4) row-chunks per batch for k_blend

// ---------------- Kernel 1: PCA -> Rodrigues -> sR, PF to ws (one block/batch)
__global__ __launch_bounds__(64) void k_pose(
    const float* __restrict__ hp, const float* __restrict__ pca,
    float* __restrict__ sRg, float* __restrict__ PFg, float* __restrict__ pen)
{
    int b = blockIdx.x, t = threadIdx.x;
    __shared__ float h45[45];
    __shared__ float sR[NJ*9];
    if (t < 45) {
        float acc = 0.0f;
        for (int k = 0; k < NCOMP; ++k) acc += hp[b*30 + 6 + k] * pca[k*45 + t];
        h45[t] = acc;
    }
    __syncthreads();
    if (t < NJ) {
        float rx, ry, rz;
        if (t == 0) { rx = hp[b*30+3]; ry = hp[b*30+4]; rz = hp[b*30+5]; }
        else        { rx = h45[(t-1)*3]; ry = h45[(t-1)*3+1]; rz = h45[(t-1)*3+2]; }
        float th = sqrtf(rx*rx + ry*ry + rz*rz + 1e-16f);
        float kx = rx/th, ky = ry/th, kz = rz/th;
        float c = cosf(th), s = sinf(th), o = 1.0f - c;
        float R[9];
        R[0] = c + o*kx*kx;      R[1] = -s*kz + o*kx*ky;  R[2] =  s*ky + o*kx*kz;
        R[3] =  s*kz + o*ky*kx;  R[4] = c + o*ky*ky;      R[5] = -s*kx + o*ky*kz;
        R[6] = -s*ky + o*kz*kx;  R[7] =  s*kx + o*kz*ky;  R[8] = c + o*kz*kz;
        #pragma unroll
        for (int i = 0; i < 9; ++i) { sR[t*9+i] = R[i]; sRg[b*(NJ*9) + t*9 + i] = R[i]; }
    }
    __syncthreads();
    for (int e = t; e < 135; e += 64) {
        int mn = e % 9;
        float d = (mn == 0 || mn == 4 || mn == 8) ? 1.0f : 0.0f;
        PFg[b*135 + e] = sR[9 + e] - d;
    }
    if (b == 0 && t == 0) *pen = 0.0f;   // d_out poisoned each iter
}

// ---------------- Kernel 2: blendshapes, one WAVE per (b, v*3+d) row.
// Lanes span the 135-dim posedirs row (coalesced 256B loads) and the 10-dim
// shapedirs row; both reductions share one 6-step butterfly pass.
__global__ __launch_bounds__(256) void k_blend(
    const float* __restrict__ vt, const float* __restrict__ sd,
    const float* __restrict__ pd, const float* __restrict__ beta,
    const float* __restrict__ PFg, float* __restrict__ VS, float* __restrict__ VP)
{
    int b = blockIdx.x / BCH, c = blockIdx.x % BCH;
    int wid = threadIdx.x >> 6, lane = threadIdx.x & 63;
    int r = c*4 + wid;                 // row within batch: v*3 + d
    if (r >= VD) return;

    const float* p  = pd  + r * 135;
    const float* pf = PFg + b * 135;
    float accP = p[lane] * pf[lane] + p[lane+64] * pf[lane+64];
    accP += (lane < 7) ? p[lane+128] * pf[lane+128] : 0.0f;

    float accS = (lane < NBETA) ? sd[r*NBETA + lane] * beta[b*NBETA + lane] : 0.0f;

    #pragma unroll
    for (int off = 32; off; off >>= 1) {
        accP += __shfl_down(accP, off, 64);
        accS += __shfl_down(accS, off, 64);
    }
    if (lane == 0) {
        float vs = vt[r] + accS;
        VS[b*VD + r] = vs;
        VP[b*VD + r] = vs + accP;
    }
}

// ---------------- Kernel 3: joints + chain + LBS + face normals + contact
// One block per batch, 256 threads (R3-proven structure; pose read from ws).
__global__ __launch_bounds__(256) void k_skel(
    const float* __restrict__ hp, const float* __restrict__ sRg,
    const float* __restrict__ Jreg, const float* __restrict__ VS,
    const float* __restrict__ VP, const float* __restrict__ W,
    const int* __restrict__ faces, const float* __restrict__ aw,
    const int* __restrict__ afi,
    float* __restrict__ verts, float4* __restrict__ PK,
    float* __restrict__ NRM, float* __restrict__ contact)
{
    int b = blockIdx.x, t = threadIdx.x;
    int lane = t & 63, wid = t >> 6;
    __shared__ float sR[NJ*9];
    __shared__ float sJ[NJ*3];
    __shared__ float4 sA4[NJ*3];      // A rows as {r0,r1,r2,t}
    __shared__ float sv[VD];
    __shared__ float sn[VD];

    if (t < NJ*9) sR[t] = sRg[b*NJ*9 + t];
    for (int i = t; i < VD; i += 256) sn[i] = 0.0f;

    // joints: wave wid handles joints 4*wid .. 4*wid+3 (VS read coalesced-ish)
    {
        float ac[12];
        #pragma unroll
        for (int q = 0; q < 12; ++q) ac[q] = 0.0f;
        for (int v = lane; v < NV; v += 64) {
            const float* p = VS + b*VD + v*3;
            float x = p[0], y = p[1], z = p[2];
            #pragma unroll
            for (int jj = 0; jj < 4; ++jj) {
                float w = Jreg[(4*wid + jj)*NV + v];
                ac[jj*3+0] += w*x; ac[jj*3+1] += w*y; ac[jj*3+2] += w*z;
            }
        }
        #pragma unroll
        for (int q = 0; q < 12; ++q)
            for (int off = 32; off; off >>= 1) ac[q] += __shfl_down(ac[q], off, 64);
        if (lane == 0) {
            #pragma unroll
            for (int q = 0; q < 12; ++q) sJ[(4*wid + q/3)*3 + (q%3)] = ac[q];
        }
    }
    __syncthreads();

    // kinematic chain: thread m (0..2) owns row m of all transforms
    if (t < 3) {
        const int par[NJ] = {-1,0,1,2,0,4,5,0,7,8,0,10,11,0,13,14};
        int m = t;
        float Tr[NJ][3], Tt[NJ];
        Tr[0][0] = sR[m*3+0]; Tr[0][1] = sR[m*3+1]; Tr[0][2] = sR[m*3+2];
        Tt[0] = sJ[m];
        #pragma unroll
        for (int j = 1; j < NJ; ++j) {
            int p = par[j];
            float t0 = sJ[j*3+0] - sJ[p*3+0];
            float t1 = sJ[j*3+1] - sJ[p*3+1];
            float t2 = sJ[j*3+2] - sJ[p*3+2];
            float a0 = Tr[p][0], a1 = Tr[p][1], a2 = Tr[p][2];
            #pragma unroll
            for (int n = 0; n < 3; ++n)
                Tr[j][n] = a0*sR[j*9+n] + a1*sR[j*9+3+n] + a2*sR[j*9+6+n];
            Tt[j] = a0*t0 + a1*t1 + a2*t2 + Tt[p];
        }
        #pragma unroll
        for (int j = 0; j < NJ; ++j) {
            float corr = Tr[j][0]*sJ[j*3] + Tr[j][1]*sJ[j*3+1] + Tr[j][2]*sJ[j*3+2];
            sA4[j*3 + m] = make_float4(Tr[j][0], Tr[j][1], Tr[j][2], Tt[j] - corr);
        }
    }
    __syncthreads();

    // LBS
    float tx = hp[b*30+0], ty = hp[b*30+1], tz = hp[b*30+2];
    for (int v = t; v < NV; v += 256) {
        float4 r0 = make_float4(0,0,0,0), r1 = make_float4(0,0,0,0), r2 = make_float4(0,0,0,0);
        const float* w = W + v * NJ;
        for (int j = 0; j < NJ; ++j) {
            float wj = w[j];
            float4 A0 = sA4[j*3+0], A1 = sA4[j*3+1], A2 = sA4[j*3+2];
            r0.x += wj*A0.x; r0.y += wj*A0.y; r0.z += wj*A0.z; r0.w += wj*A0.w;
            r1.x += wj*A1.x; r1.y += wj*A1.y; r1.z += wj*A1.z; r1.w += wj*A1.w;
            r2.x += wj*A2.x; r2.y += wj*A2.y; r2.z += wj*A2.z; r2.w += wj*A2.w;
        }
        int i = b*NV + v;
        float px = VP[b*VD + v*3], py = VP[b*VD + v*3+1], pz = VP[b*VD + v*3+2];
        float x = r0.x*px + r0.y*py + r0.z*pz + r0.w + tx;
        float y = r1.x*px + r1.y*py + r1.z*pz + r1.w + ty;
        float z = r2.x*px + r2.y*py + r2.z*pz + r2.w + tz;
        sv[v*3] = x; sv[v*3+1] = y; sv[v*3+2] = z;
        verts[i*3] = x; verts[i*3+1] = y; verts[i*3+2] = z;
        PK[i] = make_float4(x, y, z, 0.5f*(x*x + y*y + z*z));
    }
    __syncthreads();

    // face normals into LDS accumulator
    for (int f = t; f < FC; f += 256) {
        int i0 = faces[f*3], i1 = faces[f*3+1], i2 = faces[f*3+2];
        float ax = sv[i1*3+0]-sv[i0*3+0], ay = sv[i1*3+1]-sv[i0*3+1], az = sv[i1*3+2]-sv[i0*3+2];
        float bx = sv[i2*3+0]-sv[i0*3+0], by = sv[i2*3+1]-sv[i0*3+1], bz = sv[i2*3+2]-sv[i0*3+2];
        float cx = ay*bz - az*by, cy = az*bx - ax*bz, cz = ax*by - ay*bx;
        atomicAdd(&sn[i0*3+0], cx); atomicAdd(&sn[i0*3+1], cy); atomicAdd(&sn[i0*3+2], cz);
        atomicAdd(&sn[i1*3+0], cx); atomicAdd(&sn[i1*3+1], cy); atomicAdd(&sn[i1*3+2], cz);
        atomicAdd(&sn[i2*3+0], cx); atomicAdd(&sn[i2*3+1], cy); atomicAdd(&sn[i2*3+2], cz);
    }
    __syncthreads();

    // outputs: normals + contact candidates
    for (int i = t; i < VD; i += 256) NRM[b*VD + i] = sn[i];
    if (t < NA*3) {
        int a = t / 3, d = t % 3;
        float acc = 0.0f;
        #pragma unroll
        for (int k = 0; k < 3; ++k)
            acc += aw[a*3 + k] * sv[afi[a*3 + k]*3 + d];
        contact[b*NA*3 + t] = acc;
    }
}

// ---------------- Kernel 4: NN search + cmap + penetration (R3, measured-good).
__global__ __launch_bounds__(256) void k_nn(const float* __restrict__ obj,
                                            const float4* __restrict__ PK,
                                            const float* __restrict__ NRM,
                                            float* __restrict__ cmap,
                                            float* __restrict__ pen)
{
    int b = blockIdx.x >> 6;
    int n = (blockIdx.x & 63) * 256 + threadIdx.x;
    int t = threadIdx.x, lane = t & 63;
    int base = b * NV;

    float4 q[NSLOT];
    #pragma unroll
    for (int j = 0; j < NSLOT; ++j) {
        int idx = j*64 + lane;
        q[j] = (idx < NV) ? PK[base + idx] : make_float4(0.f, 0.f, 0.f, 1e30f);
    }
    const float* o = obj + (b*NOBJ + n)*3;
    float ox = o[0], oy = o[1], oz = o[2];

    float myS = 0.0f;
    int myI = 0;
    for (int p = 0; p < 64; ++p) {
        float bx = __uint_as_float(__builtin_amdgcn_readlane(__float_as_uint(ox), p));
        float by = __uint_as_float(__builtin_amdgcn_readlane(__float_as_uint(oy), p));
        float bz = __uint_as_float(__builtin_amdgcn_readlane(__float_as_uint(oz), p));
        float sb = 1e30f; int jb = 0;
        #pragma unroll
        for (int j = 0; j < NSLOT; ++j) {
            float s = fmaf(-bx, q[j].x, q[j].w);
            s = fmaf(-by, q[j].y, s);
            s = fmaf(-bz, q[j].z, s);
            if (s < sb) { sb = s; jb = j; }
        }
        int ifull = jb*64 + lane;
        float smin = sb;
        #pragma unroll
        for (int m = 1; m < 64; m <<= 1)
            smin = fminf(smin, __shfl_xor(smin, m, 64));
        unsigned long long mk = __ballot(sb == smin);
        int w = __ffsll(mk) - 1;
        int widx = __builtin_amdgcn_readlane(ifull, w);
        if (lane == p) { myS = smin; myI = widx; }
    }

    float osq = ox*ox + oy*oy + oz*oz;
    float d2 = 2.0f * myS + osq;
    cmap[b*NOBJ + n] = 2.0f / (1.0f + expf(100.0f * d2));

    float4 qq = PK[base + myI];
    float nx = NRM[(base + myI)*3 + 0];
    float ny = NRM[(base + myI)*3 + 1];
    float nz = NRM[(base + myI)*3 + 2];
    float dotp = (qq.x - ox)*nx + (qq.y - oy)*ny + (qq.z - oz)*nz;
    float p = (dotp > 0.0f) ? d2 : 0.0f;
    for (int off = 32; off; off >>= 1) p += __shfl_down(p, off, 64);
    __shared__ float wsum[4];
    if (lane == 0) wsum[t >> 6] = p;
    __syncthreads();
    if (t == 0) atomicAdd(pen, (wsum[0] + wsum[1] + wsum[2] + wsum[3]) * (1.0f / NB));
}

extern "C" void kernel_launch(void* const* d_in, const int* in_sizes, int n_in,
                              void* d_out, int out_size, void* d_ws, size_t ws_size,
                              hipStream_t stream)
{
    const float* hp    = (const float*)d_in[0];
    const float* obj   = (const float*)d_in[1];
    const float* beta  = (const float*)d_in[2];
    const float* vt    = (const float*)d_in[3];
    const float* sd    = (const float*)d_in[4];
    const float* pd    = (const float*)d_in[5];
    const float* Jreg  = (const float*)d_in[6];
    const float* W     = (const float*)d_in[7];
    const float* pca   = (const float*)d_in[8];
    const float* aw    = (const float*)d_in[9];
    const int*   faces = (const int*)d_in[10];
    const int*   afi   = (const int*)d_in[11];

    float* out     = (float*)d_out;
    float* cmap    = out;                          // 131072
    float* pen     = out + NB*NOBJ;                // 1
    float* verts   = out + NB*NOBJ + 1;            // 18672
    float* contact = out + NB*NOBJ + 1 + NB*NV*3;  // 768

    float* ws   = (float*)d_ws;
    float4* PK  = (float4*)ws;        // NB*NV float4 (16B-aligned at base)
    float* NRM  = ws + NB*NV*4;       // NB*VD
    float* VS   = NRM + NB*VD;        // NB*VD
    float* VP   = VS + NB*VD;         // NB*VD
    float* sRg  = VP + NB*VD;         // NB*144
    float* PFg  = sRg + NB*NJ*9;      // NB*135

    k_pose <<<NB, 64, 0, stream>>>(hp, pca, sRg, PFg, pen);
    k_blend<<<NB*BCH, 256, 0, stream>>>(vt, sd, pd, beta, PFg, VS, VP);
    k_skel <<<NB, 256, 0, stream>>>(hp, sRg, Jreg, VS, VP, W, faces, aw, afi,
                                    verts, PK, NRM, contact);
    k_nn   <<<NB*64, 256, 0, stream>>>(obj, PK, NRM, cmap, pen);
}